// Round 13
// baseline (86.470 us; speedup 1.0000x reference)
//
#include <hip/hip_runtime.h>

// CRF-RNN collapsed: out[t,i] = sum_j M[i,j] * orig[t,j],
//   orig[t,j] = sum_m inputs[t,j,m]*W_feat[m]
//   M = (I + B + B^2 + B^3) * diag(1/denom) + B^4
// 4 dispatches:
//   k_prep    -> B (fp32), Einv
//   k_mm      -> C = B^2                     (1 row/block, grid 256)
//   k_mm2comb -> G1,G2 in-register -> Mh/Ml  (1 row/block, grid 256)
//   k_fused   -> stream input (VGPR loads) -> split-bf16 A in LDS ->
//                MFMA with B fragments loaded DIRECTLY from L1/L2 (no B-LDS,
//                no stage-2 barriers)

#define NREG 256   // N
#define KG   16    // gaussian kernels
#define MF   8     // features

typedef unsigned short u16;
typedef __attribute__((ext_vector_type(8))) short short8;   // 8 bf16 = 4 VGPR
typedef __attribute__((ext_vector_type(4))) float f32x4;

__device__ __forceinline__ u16 bf16_rne(float x) {
    unsigned u = __float_as_uint(x);
    return (u16)((u + 0x7FFFu + ((u >> 16) & 1u)) >> 16);
}
__device__ __forceinline__ float bf16_to_f(u16 h) {
    return __uint_as_float(((unsigned)h) << 16);
}

// ---------------- K1: Kmat row, denom, B, Einv ----------------
__global__ __launch_bounds__(256) void k_prep(const float* __restrict__ kern,
                                              const float* __restrict__ Wlin,
                                              const float* __restrict__ Wfeat,
                                              float* __restrict__ B,
                                              float* __restrict__ Einv) {
    const int i = blockIdx.x, j = threadIdx.x;
    const float* kp = kern + ((size_t)i * NREG + j) * KG;
    float4 w0 = *(const float4*)(Wlin + 0);
    float4 w1 = *(const float4*)(Wlin + 4);
    float4 w2 = *(const float4*)(Wlin + 8);
    float4 w3 = *(const float4*)(Wlin + 12);
    float4 v0 = *(const float4*)(kp + 0);
    float4 v1 = *(const float4*)(kp + 4);
    float4 v2 = *(const float4*)(kp + 8);
    float4 v3 = *(const float4*)(kp + 12);
    float km = v0.x*w0.x + v0.y*w0.y + v0.z*w0.z + v0.w*w0.w
             + v1.x*w1.x + v1.y*w1.y + v1.z*w1.z + v1.w*w1.w
             + v2.x*w2.x + v2.y*w2.y + v2.z*w2.z + v2.w*w2.w
             + v3.x*w3.x + v3.y*w3.y + v3.z*w3.z + v3.w*w3.w;

    __shared__ float red[256];
    red[j] = km;
    __syncthreads();
    for (int s = 128; s > 0; s >>= 1) {
        if (j < s) red[j] += red[j + s];
        __syncthreads();
    }
    __shared__ float sden;
    if (j == 0) {
        float fw = 0.f;
#pragma unroll
        for (int m = 0; m < MF; ++m) fw += Wfeat[m];
        float den = fw + 2.f * red[0];
        sden = den;
        Einv[i] = 1.f / den;
    }
    __syncthreads();
    B[(size_t)i * NREG + j] = 2.f * km / sden;
}

// ---------------- 1-row matmul helper: acc = A-row(i) * Bm -----------------
#define MM1_BODY(Ar, Bm, acc)                                                 \
    _Pragma("unroll 4")                                                       \
    for (int l = 0; l < NREG; l += 8) {                                       \
        float b0 = Bm[(size_t)(l + 0) * NREG + tid];                          \
        float b1 = Bm[(size_t)(l + 1) * NREG + tid];                          \
        float b2 = Bm[(size_t)(l + 2) * NREG + tid];                          \
        float b3 = Bm[(size_t)(l + 3) * NREG + tid];                          \
        float b4 = Bm[(size_t)(l + 4) * NREG + tid];                          \
        float b5 = Bm[(size_t)(l + 5) * NREG + tid];                          \
        float b6 = Bm[(size_t)(l + 6) * NREG + tid];                          \
        float b7 = Bm[(size_t)(l + 7) * NREG + tid];                          \
        acc += Ar[l+0]*b0 + Ar[l+1]*b1 + Ar[l+2]*b2 + Ar[l+3]*b3              \
             + Ar[l+4]*b4 + Ar[l+5]*b5 + Ar[l+6]*b6 + Ar[l+7]*b7;             \
    }

// K2: C = B*B   (grid 256, 1 row/block)
__global__ __launch_bounds__(256) void k_mm(const float* __restrict__ A,
                                            const float* __restrict__ Bm,
                                            float* __restrict__ Out) {
    const int tid = threadIdx.x;
    const int i = blockIdx.x;
    __shared__ float Ar[NREG];
    Ar[tid] = A[(size_t)i * NREG + tid];
    __syncthreads();
    float acc = 0.f;
    MM1_BODY(Ar, Bm, acc)
    Out[(size_t)i * NREG + tid] = acc;
}

// K3: G1 = (B*C) row, G2 = (C*C) row in-register -> Mh/Ml row
__global__ __launch_bounds__(256) void k_mm2comb(const float* __restrict__ B,
                                                 const float* __restrict__ C,
                                                 const float* __restrict__ Einv,
                                                 u16* __restrict__ Mh,
                                                 u16* __restrict__ Ml) {
    const int tid = threadIdx.x;
    const int i = blockIdx.x;
    __shared__ float Ar[NREG];

    Ar[tid] = B[(size_t)i * NREG + tid];
    __syncthreads();
    float g1 = 0.f;
    MM1_BODY(Ar, C, g1)
    __syncthreads();                      // before overwriting Ar
    Ar[tid] = C[(size_t)i * NREG + tid];
    __syncthreads();
    float g2 = 0.f;
    MM1_BODY(Ar, C, g2)

    const size_t idx = (size_t)i * NREG + tid;
    float v = ((i == tid) ? 1.f : 0.f) + B[idx] + C[idx] + g1;
    v = v * Einv[tid] + g2;
    u16 h = bf16_rne(v);
    Mh[idx] = h;
    Ml[idx] = bf16_rne(v - bf16_to_f(h));
}

// ---------------- K4: fused stream + MFMA GEMM -----------------------------
// 512 blocks x 256 thr (4 waves), 32 t-rows/block, LDS 32 KB (A-splits only)
// -> 3 blocks/CU (12 streaming waves/CU).
// Stage 1 (r11-verified): 64 independent float4 loads/thread, feature-reduce,
//   split-bf16, chunk-XOR-swizzled ds_write into Ah/Al.
// Stage 2: ONE barrier, then 8 K-steps of 32 j: A frags via swizzled
//   ds_read_b128; B frags loaded directly from Mh/Ml (global; L1-resident --
//   per-step working set 8 KB, M total 256 KB). 3-product split-bf16 MFMA.
//   B address = r8-verified mapping with LDS swizzle algebraically removed:
//   lane reads Mh[irow*256 + kk*32 + (lane>>4)*8], irow=(nh+n)*16+(lane&15).
__global__ __launch_bounds__(256, 3) void k_fused(const float* __restrict__ in,
                                                  const float* __restrict__ Wfeat,
                                                  const u16* __restrict__ Mh,
                                                  const u16* __restrict__ Ml,
                                                  float* __restrict__ out) {
    __shared__ __align__(16) u16 Ah[32 * 256];   // 16 KB
    __shared__ __align__(16) u16 Al[32 * 256];   // 16 KB
    const int tid = threadIdx.x, lane = tid & 63, wid = tid >> 6;  // wid 0..3
    const size_t t0 = (size_t)blockIdx.x * 32;

    float4 wa = *(const float4*)(Wfeat);
    float4 wb = *(const float4*)(Wfeat + 4);

    // ---- stage 1: thread (r = tid>>3, s = tid&7) covers row r, cell-pairs
    // j0 = q*16 + 2s (q = 0..15); 64 B contiguous per (thread,q).
    {
        const int r = tid >> 3, s = tid & 7;
        const float* rowp = in + (t0 + r) * (NREG * MF);
#pragma unroll
        for (int b = 0; b < 4; ++b) {
            float4 v[4][4];
#pragma unroll
            for (int qq = 0; qq < 4; ++qq) {
                const float* p = rowp + (b * 4 + qq) * 128 + s * 16;
#pragma unroll
                for (int k = 0; k < 4; ++k) v[qq][k] = *(const float4*)(p + k * 4);
            }
#pragma unroll
            for (int qq = 0; qq < 4; ++qq) {
                const int q = b * 4 + qq;
                float o0 = v[qq][0].x*wa.x + v[qq][0].y*wa.y + v[qq][0].z*wa.z + v[qq][0].w*wa.w
                         + v[qq][1].x*wb.x + v[qq][1].y*wb.y + v[qq][1].z*wb.z + v[qq][1].w*wb.w;
                float o1 = v[qq][2].x*wa.x + v[qq][2].y*wa.y + v[qq][2].z*wa.z + v[qq][2].w*wa.w
                         + v[qq][3].x*wb.x + v[qq][3].y*wb.y + v[qq][3].z*wb.z + v[qq][3].w*wb.w;
                u16 h0 = bf16_rne(o0), l0 = bf16_rne(o0 - bf16_to_f(h0));
                u16 h1 = bf16_rne(o1), l1 = bf16_rne(o1 - bf16_to_f(h1));
                const int j0 = q * 16 + 2 * s;
                const int cs = (j0 >> 3) ^ (r & 7);       // chunk swizzle
                const int idx = r * 256 + cs * 8 + (j0 & 7);   // even -> 4B ok
                *(unsigned*)&Ah[idx] = (unsigned)h0 | ((unsigned)h1 << 16);
                *(unsigned*)&Al[idx] = (unsigned)l0 | ((unsigned)l1 << 16);
            }
        }
    }
    __syncthreads();     // A-splits resident

    // ---- stage 2: no barriers, no B staging.
    const int m = wid >> 1, nh = (wid & 1) * 8;
    const int mrow = m * 16 + (lane & 15);
    f32x4 acc[8];
#pragma unroll
    for (int n = 0; n < 8; ++n) acc[n] = (f32x4){0.f, 0.f, 0.f, 0.f};

    // per-lane fixed B base: row (nh*16 + lane&15), k-quad (lane>>4)
    const size_t boff = (size_t)(nh * 16 + (lane & 15)) * NREG + (lane >> 4) * 8;
    const u16* bh = Mh + boff;
    const u16* bl = Ml + boff;

    for (int kk = 0; kk < 8; ++kk) {
        const int ach = ((kk * 4 + (lane >> 4)) ^ (lane & 7)) * 8;
        short8 a_h = *(const short8*)&Ah[mrow * 256 + ach];
        short8 a_l = *(const short8*)&Al[mrow * 256 + ach];
#pragma unroll
        for (int n = 0; n < 8; ++n) {
            short8 b_h = *(const short8*)(bh + n * 16 * NREG + kk * 32);
            short8 b_l = *(const short8*)(bl + n * 16 * NREG + kk * 32);
            acc[n] = __builtin_amdgcn_mfma_f32_16x16x32_bf16(a_h, b_h, acc[n], 0, 0, 0);
            acc[n] = __builtin_amdgcn_mfma_f32_16x16x32_bf16(a_h, b_l, acc[n], 0, 0, 0);
            acc[n] = __builtin_amdgcn_mfma_f32_16x16x32_bf16(a_l, b_h, acc[n], 0, 0, 0);
        }
    }

    // ---- epilogue: D col = lane&15 (i), row = (lane>>4)*4 + reg (t)
    const size_t tb = t0 + m * 16 + (lane >> 4) * 4;
#pragma unroll
    for (int n = 0; n < 8; ++n) {
#pragma unroll
        for (int r2 = 0; r2 < 4; ++r2) {
            out[(tb + r2) * NREG + (nh + n) * 16 + (lane & 15)] = acc[n][r2];
        }
    }
}

extern "C" void kernel_launch(void* const* d_in, const int* in_sizes, int n_in,
                              void* d_out, int out_size, void* d_ws, size_t ws_size,
                              hipStream_t stream) {
    const float* inputs  = (const float*)d_in[0];  // (16384, 256, 8)
    const float* kernels = (const float*)d_in[1];  // (256, 256, 16)
    const float* Wfeat   = (const float*)d_in[2];  // (1, 8)
    const float* Wlin    = (const float*)d_in[3];  // (1, 16)
    float* out = (float*)d_out;                    // (16384, 256)

    float* ws   = (float*)d_ws;                    // ~770 KB
    float* B    = ws;                              // 65536 f
    float* C    = B  + NREG * NREG;                // 65536 f (B^2)
    float* Einv = C  + NREG * NREG;                // 256 f
    u16*   Mh   = (u16*)(Einv + NREG);             // 65536 u16 (16B-aligned)
    u16*   Ml   = Mh + NREG * NREG;                // 65536 u16

    k_prep    <<<256, 256, 0, stream>>>(kernels, Wlin, Wfeat, B, Einv);
    k_mm      <<<256, 256, 0, stream>>>(B, B, C);
    k_mm2comb <<<256, 256, 0, stream>>>(B, C, Einv, Mh, Ml);
    k_fused   <<<512, 256, 0, stream>>>(inputs, Wfeat, Mh, Ml, out);
}

// Round 14
// 56.915 us; speedup vs baseline: 1.5193x; 1.5193x over previous
//
#include <hip/hip_runtime.h>

// CRF-RNN collapsed: out[t,i] = sum_j M[i,j] * orig[t,j],
//   orig[t,j] = sum_m inputs[t,j,m]*W_feat[m]
//   M = (I + B + B^2 + B^3) * diag(1/denom) + B^4
// 4 dispatches (r9's verified k_main + r12's verified fused setup):
//   k_prep    -> B (fp32), Einv
//   k_mm      -> C = B^2                     (1 row/block, grid 256)
//   k_mm2comb -> G1,G2 in-register -> Mh/Ml  (1 row/block, grid 256)
//   k_main    -> r9: 8-wave block, async ring stage-1, B-panel MFMA stage-2

#define NREG 256   // N
#define KG   16    // gaussian kernels
#define MF   8     // features

typedef unsigned short u16;
typedef __attribute__((ext_vector_type(8))) short short8;   // 8 bf16 = 4 VGPR
typedef __attribute__((ext_vector_type(4))) float f32x4;

__device__ __forceinline__ void async_copy16(const void* g, void* l) {
    __builtin_amdgcn_global_load_lds(
        (const __attribute__((address_space(1))) void*)g,
        (__attribute__((address_space(3))) void*)l,
        16, 0, 0);
}

__device__ __forceinline__ u16 bf16_rne(float x) {
    unsigned u = __float_as_uint(x);
    return (u16)((u + 0x7FFFu + ((u >> 16) & 1u)) >> 16);
}
__device__ __forceinline__ float bf16_to_f(u16 h) {
    return __uint_as_float(((unsigned)h) << 16);
}

// ---------------- K1: Kmat row, denom, B, Einv ----------------
__global__ __launch_bounds__(256) void k_prep(const float* __restrict__ kern,
                                              const float* __restrict__ Wlin,
                                              const float* __restrict__ Wfeat,
                                              float* __restrict__ B,
                                              float* __restrict__ Einv) {
    const int i = blockIdx.x, j = threadIdx.x;
    const float* kp = kern + ((size_t)i * NREG + j) * KG;
    float4 w0 = *(const float4*)(Wlin + 0);
    float4 w1 = *(const float4*)(Wlin + 4);
    float4 w2 = *(const float4*)(Wlin + 8);
    float4 w3 = *(const float4*)(Wlin + 12);
    float4 v0 = *(const float4*)(kp + 0);
    float4 v1 = *(const float4*)(kp + 4);
    float4 v2 = *(const float4*)(kp + 8);
    float4 v3 = *(const float4*)(kp + 12);
    float km = v0.x*w0.x + v0.y*w0.y + v0.z*w0.z + v0.w*w0.w
             + v1.x*w1.x + v1.y*w1.y + v1.z*w1.z + v1.w*w1.w
             + v2.x*w2.x + v2.y*w2.y + v2.z*w2.z + v2.w*w2.w
             + v3.x*w3.x + v3.y*w3.y + v3.z*w3.z + v3.w*w3.w;

    __shared__ float red[256];
    red[j] = km;
    __syncthreads();
    for (int s = 128; s > 0; s >>= 1) {
        if (j < s) red[j] += red[j + s];
        __syncthreads();
    }
    __shared__ float sden;
    if (j == 0) {
        float fw = 0.f;
#pragma unroll
        for (int m = 0; m < MF; ++m) fw += Wfeat[m];
        float den = fw + 2.f * red[0];
        sden = den;
        Einv[i] = 1.f / den;
    }
    __syncthreads();
    B[(size_t)i * NREG + j] = 2.f * km / sden;
}

// ---------------- 1-row matmul helper: acc = A-row(i) * Bm -----------------
#define MM1_BODY(Ar, Bm, acc)                                                 \
    _Pragma("unroll 4")                                                       \
    for (int l = 0; l < NREG; l += 8) {                                       \
        float b0 = Bm[(size_t)(l + 0) * NREG + tid];                          \
        float b1 = Bm[(size_t)(l + 1) * NREG + tid];                          \
        float b2 = Bm[(size_t)(l + 2) * NREG + tid];                          \
        float b3 = Bm[(size_t)(l + 3) * NREG + tid];                          \
        float b4 = Bm[(size_t)(l + 4) * NREG + tid];                          \
        float b5 = Bm[(size_t)(l + 5) * NREG + tid];                          \
        float b6 = Bm[(size_t)(l + 6) * NREG + tid];                          \
        float b7 = Bm[(size_t)(l + 7) * NREG + tid];                          \
        acc += Ar[l+0]*b0 + Ar[l+1]*b1 + Ar[l+2]*b2 + Ar[l+3]*b3              \
             + Ar[l+4]*b4 + Ar[l+5]*b5 + Ar[l+6]*b6 + Ar[l+7]*b7;             \
    }

// K2: C = B*B   (grid 256, 1 row/block)
__global__ __launch_bounds__(256) void k_mm(const float* __restrict__ A,
                                            const float* __restrict__ Bm,
                                            float* __restrict__ Out) {
    const int tid = threadIdx.x;
    const int i = blockIdx.x;
    __shared__ float Ar[NREG];
    Ar[tid] = A[(size_t)i * NREG + tid];
    __syncthreads();
    float acc = 0.f;
    MM1_BODY(Ar, Bm, acc)
    Out[(size_t)i * NREG + tid] = acc;
}

// K3: G1 = (B*C) row, G2 = (C*C) row in-register -> Mh/Ml row
__global__ __launch_bounds__(256) void k_mm2comb(const float* __restrict__ B,
                                                 const float* __restrict__ C,
                                                 const float* __restrict__ Einv,
                                                 u16* __restrict__ Mh,
                                                 u16* __restrict__ Ml) {
    const int tid = threadIdx.x;
    const int i = blockIdx.x;
    __shared__ float Ar[NREG];

    Ar[tid] = B[(size_t)i * NREG + tid];
    __syncthreads();
    float g1 = 0.f;
    MM1_BODY(Ar, C, g1)
    __syncthreads();                      // before overwriting Ar
    Ar[tid] = C[(size_t)i * NREG + tid];
    __syncthreads();
    float g2 = 0.f;
    MM1_BODY(Ar, C, g2)

    const size_t idx = (size_t)i * NREG + tid;
    float v = ((i == tid) ? 1.f : 0.f) + B[idx] + C[idx] + g1;
    v = v * Einv[tid] + g2;
    u16 h = bf16_rne(v);
    Mh[idx] = h;
    Ml[idx] = bf16_rne(v - bf16_to_f(h));
}

// ---------------- K4: fused feature-reduce + MFMA GEMM (r9, verified) ------
// Block = 512 thr (8 waves = 2/SIMD), 64 t-rows; grid 256 (1 block/CU).
// Stage 1: per-wave 4-deep async ring (2 KB chunks), 8 loads in flight/wave.
// Stage 2: 4 K-panels of 64 j; B panels live in the SAME LDS as the ring
//          (ring dead after stage-1 sync). Split-bf16, 3 MFMA products.
// XOR swizzle (r8-verified): 16B-chunk index ^= (row & 7).
__global__ __launch_bounds__(512, 1) void k_main(const float* __restrict__ in,
                                                 const float* __restrict__ Wfeat,
                                                 const u16* __restrict__ Mh,
                                                 const u16* __restrict__ Ml,
                                                 float* __restrict__ out) {
    __shared__ __align__(16) u16 Ah[64 * 256];       // 32 KB
    __shared__ __align__(16) u16 Al[64 * 256];       // 32 KB
    __shared__ __align__(16) u16 BhBl[2][256 * 64];  // 64 KB: B panels / ring union
    u16* Bh = &BhBl[0][0];
    u16* Bl = &BhBl[1][0];
    float (*raws)[4][512] = (float (*)[4][512])&BhBl[0][0];  // 8w x 4slots x 2KB

    const int tid = threadIdx.x, lane = tid & 63, wid = tid >> 6;  // wid 0..7
    const size_t t0 = (size_t)blockIdx.x * 64;

    // Wfeat live before any async issue (its waitcnt resolves before the ring)
    float4 wa = *(const float4*)(Wfeat);
    float4 wb = *(const float4*)(Wfeat + 4);
    asm volatile("" :: "v"(wa.x), "v"(wa.y), "v"(wa.z), "v"(wa.w),
                       "v"(wb.x), "v"(wb.y), "v"(wb.z), "v"(wb.w));

    // ---- stage 1: wave streams its 8 t-rows as 32 chunks of 2 KB.
    // chunk c: row tl=c>>2, quarter q=c&3; 2 asyncs of 1 KB; slot c&3.
    const float* wbase = in + (t0 + wid * 8) * (NREG * MF);
#pragma unroll
    for (int c = 0; c < 4; ++c) {       // prologue: fill all 4 slots
        const float* src = wbase + (size_t)(c >> 2) * 2048 + (size_t)(c & 3) * 512;
        async_copy16(src + lane * 4,       &raws[wid][c & 3][0]);
        async_copy16(src + 256 + lane * 4, &raws[wid][c & 3][256]);
    }
#pragma unroll
    for (int c = 0; c < 32; ++c) {
        // wait for oldest chunk (2 loads); tail counts shrink to 0
        if (c < 29)      asm volatile("s_waitcnt vmcnt(6)" ::: "memory");
        else if (c == 29) asm volatile("s_waitcnt vmcnt(4)" ::: "memory");
        else if (c == 30) asm volatile("s_waitcnt vmcnt(2)" ::: "memory");
        else              asm volatile("s_waitcnt vmcnt(0)" ::: "memory");
        __builtin_amdgcn_sched_barrier(0);
        const float* rb = &raws[wid][c & 3][lane * 8];
        float4 a0 = *(const float4*)(rb + 0);
        float4 a1 = *(const float4*)(rb + 4);
        // WAR fence (r7-verified): slot reads must RETURN before its refill
        // is issued (ds_read vs VMEM->LDS write are not cross-ordered).
        asm volatile("s_waitcnt lgkmcnt(0)" ::: "memory");
        __builtin_amdgcn_sched_barrier(0);
        if (c + 4 < 32) {
            const int cn = c + 4;
            const float* src = wbase + (size_t)(cn >> 2) * 2048 + (size_t)(cn & 3) * 512;
            async_copy16(src + lane * 4,       &raws[wid][cn & 3][0]);
            async_copy16(src + 256 + lane * 4, &raws[wid][cn & 3][256]);
        }
        float o = a0.x*wa.x + a0.y*wa.y + a0.z*wa.z + a0.w*wa.w
                + a1.x*wb.x + a1.y*wb.y + a1.z*wb.z + a1.w*wb.w;
        u16 h  = bf16_rne(o);
        u16 l2 = bf16_rne(o - bf16_to_f(h));
        const int tl = c >> 2, q = c & 3;
        const int t = wid * 8 + tl;                 // t&7 == tl
        const int chunk = q * 8 + (lane >> 3);      // j>>3 within row
        const int swz = chunk ^ tl;                 // low-3-bit XOR swizzle
        const int idx = t * 256 + swz * 8 + (lane & 7);
        Ah[idx] = h;
        Al[idx] = l2;
    }
    __syncthreads();   // ring fully consumed; A splits resident; vmcnt drained

    // ---- stage 2: 4 K-panels of 64 j. Wave w: m-tile w>>1, n-half w&1.
    const int mrow = (wid >> 1) * 16 + (lane & 15);
    const int nh   = (wid & 1) * 8;
    f32x4 acc[8];
#pragma unroll
    for (int n = 0; n < 8; ++n) acc[n] = (f32x4){0.f, 0.f, 0.f, 0.f};

    for (int p = 0; p < 4; ++p) {
        if (p) __syncthreads();      // previous panel fully consumed
        // stage B panel p: 64 gll of 1 KB (8 i-rows each); 8 per wave.
        // dest linear; source pre-swizzled: src chunk = (lds chunk)^(irow&7)
#pragma unroll
        for (int s = 0; s < 8; ++s) {
            const int g = s * 8 + wid;              // 0..63
            const int i0 = (g & 31) * 8;
            const u16* sg = (g >> 5) ? Ml : Mh;
            u16* dg = (g >> 5) ? Bl : Bh;
            const int irow = i0 + (lane >> 3);
            const int ch = (lane & 7) ^ (lane >> 3);
            async_copy16(sg + (size_t)irow * NREG + p * 64 + ch * 8,
                         dg + i0 * 64);
        }
        __syncthreads();             // drains vmcnt -> panel resident

#pragma unroll
        for (int kst = 0; kst < 2; ++kst) {
            const int achunk = (8 * p + 4 * kst + (lane >> 4)) ^ (lane & 7);
            short8 a_h = *(const short8*)(Ah + mrow * 256 + achunk * 8);
            short8 a_l = *(const short8*)(Al + mrow * 256 + achunk * 8);
#pragma unroll
            for (int n = 0; n < 8; ++n) {
                const int irow = (nh + n) * 16 + (lane & 15);
                const int bchunk = (4 * kst + (lane >> 4)) ^ (lane & 7);
                short8 b_h = *(const short8*)(Bh + irow * 64 + bchunk * 8);
                short8 b_l = *(const short8*)(Bl + irow * 64 + bchunk * 8);
                acc[n] = __builtin_amdgcn_mfma_f32_16x16x32_bf16(a_h, b_h, acc[n], 0, 0, 0);
                acc[n] = __builtin_amdgcn_mfma_f32_16x16x32_bf16(a_h, b_l, acc[n], 0, 0, 0);
                acc[n] = __builtin_amdgcn_mfma_f32_16x16x32_bf16(a_l, b_h, acc[n], 0, 0, 0);
            }
        }
    }

    // ---- epilogue: D col = lane&15 (i), row = (lane>>4)*4 + reg (t)
    const size_t tbase = t0 + (wid >> 1) * 16 + (lane >> 4) * 4;
#pragma unroll
    for (int n = 0; n < 8; ++n) {
#pragma unroll
        for (int r = 0; r < 4; ++r) {
            out[(tbase + r) * NREG + (nh + n) * 16 + (lane & 15)] = acc[n][r];
        }
    }
}

extern "C" void kernel_launch(void* const* d_in, const int* in_sizes, int n_in,
                              void* d_out, int out_size, void* d_ws, size_t ws_size,
                              hipStream_t stream) {
    const float* inputs  = (const float*)d_in[0];  // (16384, 256, 8)
    const float* kernels = (const float*)d_in[1];  // (256, 256, 16)
    const float* Wfeat   = (const float*)d_in[2];  // (1, 8)
    const float* Wlin    = (const float*)d_in[3];  // (1, 16)
    float* out = (float*)d_out;                    // (16384, 256)

    float* ws   = (float*)d_ws;                    // ~770 KB
    float* B    = ws;                              // 65536 f
    float* C    = B  + NREG * NREG;                // 65536 f (B^2)
    float* Einv = C  + NREG * NREG;                // 256 f
    u16*   Mh   = (u16*)(Einv + NREG);             // 65536 u16 (16B-aligned)
    u16*   Ml   = Mh + NREG * NREG;                // 65536 u16

    k_prep    <<<256, 256, 0, stream>>>(kernels, Wlin, Wfeat, B, Einv);
    k_mm      <<<256, 256, 0, stream>>>(B, B, C);
    k_mm2comb <<<256, 256, 0, stream>>>(B, C, Einv, Mh, Ml);
    k_main    <<<256, 512, 0, stream>>>(inputs, Wfeat, Mh, Ml, out);
}

// Round 15
// 56.343 us; speedup vs baseline: 1.5347x; 1.0102x over previous
//
#include <hip/hip_runtime.h>

// CRF-RNN collapsed: out[t,i] = sum_j M[i,j] * orig[t,j],
//   orig[t,j] = sum_m inputs[t,j,m]*W_feat[m]
//   M = (I + B + B^2 + B^3) * diag(1/denom) + B^4
// 4 dispatches:
//   k_prep    -> B (fp32), Einv
//   k_mm      -> C = B^2                     (1 row/block, grid 256)
//   k_mm2comb -> G1,G2 in-register -> Mh/Ml  (1 row/block, grid 256)
//   k_main    -> stage-1: DIRECT global->VGPR stream (inline-asm batched
//                loads, no LDS ring) -> split-bf16 A in LDS;
//                stage-2: r9-verified B-panel MFMA.

#define NREG 256   // N
#define KG   16    // gaussian kernels
#define MF   8     // features

typedef unsigned short u16;
typedef __attribute__((ext_vector_type(8))) short short8;   // 8 bf16 = 4 VGPR
typedef __attribute__((ext_vector_type(4))) float f32x4;

__device__ __forceinline__ void async_copy16(const void* g, void* l) {
    __builtin_amdgcn_global_load_lds(
        (const __attribute__((address_space(1))) void*)g,
        (__attribute__((address_space(3))) void*)l,
        16, 0, 0);
}

// inline-asm 16B global load: compiler must allocate the tuple and issue the
// load where written -- it cannot serialize the batch (r11/r13 failure mode).
__device__ __forceinline__ f32x4 ld16(const float* p) {
    f32x4 d;
    asm volatile("global_load_dwordx4 %0, %1, off" : "=v"(d) : "v"(p));
    return d;
}

__device__ __forceinline__ u16 bf16_rne(float x) {
    unsigned u = __float_as_uint(x);
    return (u16)((u + 0x7FFFu + ((u >> 16) & 1u)) >> 16);
}
__device__ __forceinline__ float bf16_to_f(u16 h) {
    return __uint_as_float(((unsigned)h) << 16);
}

// ---------------- K1: Kmat row, denom, B, Einv ----------------
__global__ __launch_bounds__(256) void k_prep(const float* __restrict__ kern,
                                              const float* __restrict__ Wlin,
                                              const float* __restrict__ Wfeat,
                                              float* __restrict__ B,
                                              float* __restrict__ Einv) {
    const int i = blockIdx.x, j = threadIdx.x;
    const float* kp = kern + ((size_t)i * NREG + j) * KG;
    float4 w0 = *(const float4*)(Wlin + 0);
    float4 w1 = *(const float4*)(Wlin + 4);
    float4 w2 = *(const float4*)(Wlin + 8);
    float4 w3 = *(const float4*)(Wlin + 12);
    float4 v0 = *(const float4*)(kp + 0);
    float4 v1 = *(const float4*)(kp + 4);
    float4 v2 = *(const float4*)(kp + 8);
    float4 v3 = *(const float4*)(kp + 12);
    float km = v0.x*w0.x + v0.y*w0.y + v0.z*w0.z + v0.w*w0.w
             + v1.x*w1.x + v1.y*w1.y + v1.z*w1.z + v1.w*w1.w
             + v2.x*w2.x + v2.y*w2.y + v2.z*w2.z + v2.w*w2.w
             + v3.x*w3.x + v3.y*w3.y + v3.z*w3.z + v3.w*w3.w;

    __shared__ float red[256];
    red[j] = km;
    __syncthreads();
    for (int s = 128; s > 0; s >>= 1) {
        if (j < s) red[j] += red[j + s];
        __syncthreads();
    }
    __shared__ float sden;
    if (j == 0) {
        float fw = 0.f;
#pragma unroll
        for (int m = 0; m < MF; ++m) fw += Wfeat[m];
        float den = fw + 2.f * red[0];
        sden = den;
        Einv[i] = 1.f / den;
    }
    __syncthreads();
    B[(size_t)i * NREG + j] = 2.f * km / sden;
}

// ---------------- 1-row matmul helper: acc = A-row(i) * Bm -----------------
#define MM1_BODY(Ar, Bm, acc)                                                 \
    _Pragma("unroll 4")                                                       \
    for (int l = 0; l < NREG; l += 8) {                                       \
        float b0 = Bm[(size_t)(l + 0) * NREG + tid];                          \
        float b1 = Bm[(size_t)(l + 1) * NREG + tid];                          \
        float b2 = Bm[(size_t)(l + 2) * NREG + tid];                          \
        float b3 = Bm[(size_t)(l + 3) * NREG + tid];                          \
        float b4 = Bm[(size_t)(l + 4) * NREG + tid];                          \
        float b5 = Bm[(size_t)(l + 5) * NREG + tid];                          \
        float b6 = Bm[(size_t)(l + 6) * NREG + tid];                          \
        float b7 = Bm[(size_t)(l + 7) * NREG + tid];                          \
        acc += Ar[l+0]*b0 + Ar[l+1]*b1 + Ar[l+2]*b2 + Ar[l+3]*b3              \
             + Ar[l+4]*b4 + Ar[l+5]*b5 + Ar[l+6]*b6 + Ar[l+7]*b7;             \
    }

// K2: C = B*B   (grid 256, 1 row/block)
__global__ __launch_bounds__(256) void k_mm(const float* __restrict__ A,
                                            const float* __restrict__ Bm,
                                            float* __restrict__ Out) {
    const int tid = threadIdx.x;
    const int i = blockIdx.x;
    __shared__ float Ar[NREG];
    Ar[tid] = A[(size_t)i * NREG + tid];
    __syncthreads();
    float acc = 0.f;
    MM1_BODY(Ar, Bm, acc)
    Out[(size_t)i * NREG + tid] = acc;
}

// K3: G1 = (B*C) row, G2 = (C*C) row in-register -> Mh/Ml row
__global__ __launch_bounds__(256) void k_mm2comb(const float* __restrict__ B,
                                                 const float* __restrict__ C,
                                                 const float* __restrict__ Einv,
                                                 u16* __restrict__ Mh,
                                                 u16* __restrict__ Ml) {
    const int tid = threadIdx.x;
    const int i = blockIdx.x;
    __shared__ float Ar[NREG];

    Ar[tid] = B[(size_t)i * NREG + tid];
    __syncthreads();
    float g1 = 0.f;
    MM1_BODY(Ar, C, g1)
    __syncthreads();                      // before overwriting Ar
    Ar[tid] = C[(size_t)i * NREG + tid];
    __syncthreads();
    float g2 = 0.f;
    MM1_BODY(Ar, C, g2)

    const size_t idx = (size_t)i * NREG + tid;
    float v = ((i == tid) ? 1.f : 0.f) + B[idx] + C[idx] + g1;
    v = v * Einv[tid] + g2;
    u16 h = bf16_rne(v);
    Mh[idx] = h;
    Ml[idx] = bf16_rne(v - bf16_to_f(h));
}

// ---------------- K4: fused feature-reduce + MFMA GEMM ---------------------
// Block = 512 thr (8 waves = 2/SIMD), 64 t-rows; grid 256 (1 block/CU).
// Stage 1 (NEW): wave w owns rows w*8..w*8+7. Per row, lane reads 32 B
//   (one orig value j = dq*64+lane per 8-float group, dq=0..3) as 8
//   inline-asm global_load_dwordx4; 2 rows ping-pong in registers
//   (16 loads in flight), counted vmcnt(8) + sched_barrier per row.
//   No LDS ring, no lgkm WAR fences.
// Stage 2 (r9/r14-verified, byte-identical): 4 K-panels of 64 j via
//   global_load_lds, split-bf16, 3 MFMA products.
// XOR swizzle (r8-verified): 16B-chunk index ^= (row & 7).
__global__ __launch_bounds__(512, 1) void k_main(const float* __restrict__ in,
                                                 const float* __restrict__ Wfeat,
                                                 const u16* __restrict__ Mh,
                                                 const u16* __restrict__ Ml,
                                                 float* __restrict__ out) {
    __shared__ __align__(16) u16 Ah[64 * 256];       // 32 KB
    __shared__ __align__(16) u16 Al[64 * 256];       // 32 KB
    __shared__ __align__(16) u16 Bh[256 * 64];       // 32 KB
    __shared__ __align__(16) u16 Bl[256 * 64];       // 32 KB

    const int tid = threadIdx.x, lane = tid & 63, wid = tid >> 6;  // wid 0..7
    const size_t t0 = (size_t)blockIdx.x * 64;

    // Wfeat live (and its waitcnt retired) BEFORE any inline-asm load, so the
    // compiler's own vmcnt bookkeeping can't drain our pipeline mid-stream.
    float4 wa = *(const float4*)(Wfeat);
    float4 wb = *(const float4*)(Wfeat + 4);
    asm volatile("" :: "v"(wa.x), "v"(wa.y), "v"(wa.z), "v"(wa.w),
                       "v"(wb.x), "v"(wb.y), "v"(wb.z), "v"(wb.w));

    // ---- stage 1 ----
    const float* rowbase = in + (t0 + wid * 8) * (NREG * MF);

#define ISSUE(BUF, TL)                                                        \
    {                                                                         \
        const float* rp_ = rowbase + (TL) * 2048 + lane * 8;                  \
        _Pragma("unroll")                                                     \
        for (int q = 0; q < 8; ++q)                                           \
            BUF[q] = ld16(rp_ + (q >> 1) * 512 + (q & 1) * 4);                \
    }

#define PROCESS(BUF, TL)                                                      \
    {                                                                         \
        const int t_ = wid * 8 + (TL);                                        \
        _Pragma("unroll")                                                     \
        for (int dq = 0; dq < 4; ++dq) {                                      \
            f32x4 a0 = BUF[2 * dq], a1 = BUF[2 * dq + 1];                     \
            float o = a0[0]*wa.x + a0[1]*wa.y + a0[2]*wa.z + a0[3]*wa.w       \
                    + a1[0]*wb.x + a1[1]*wb.y + a1[2]*wb.z + a1[3]*wb.w;      \
            u16 h_ = bf16_rne(o);                                             \
            u16 l_ = bf16_rne(o - bf16_to_f(h_));                             \
            const int j_ = dq * 64 + lane;                                    \
            const int idx_ = t_ * 256 + (((j_ >> 3) ^ (TL)) * 8) + (j_ & 7);  \
            Ah[idx_] = h_;                                                    \
            Al[idx_] = l_;                                                    \
        }                                                                     \
    }

#define WAITV(N)  asm volatile("s_waitcnt vmcnt(" #N ")" ::: "memory");       \
                  __builtin_amdgcn_sched_barrier(0);

    f32x4 ba[8], bb[8];
    ISSUE(ba, 0)
    ISSUE(bb, 1)
    WAITV(8)  PROCESS(ba, 0)  ISSUE(ba, 2)
    WAITV(8)  PROCESS(bb, 1)  ISSUE(bb, 3)
    WAITV(8)  PROCESS(ba, 2)  ISSUE(ba, 4)
    WAITV(8)  PROCESS(bb, 3)  ISSUE(bb, 5)
    WAITV(8)  PROCESS(ba, 4)  ISSUE(ba, 6)
    WAITV(8)  PROCESS(bb, 5)  ISSUE(bb, 7)
    WAITV(8)  PROCESS(ba, 6)
    WAITV(0)  PROCESS(bb, 7)

    __syncthreads();   // A splits resident (compiler drains lgkm for ds_writes)

    // ---- stage 2: 4 K-panels of 64 j. Wave w: m-tile w>>1, n-half w&1.
    const int mrow = (wid >> 1) * 16 + (lane & 15);
    const int nh   = (wid & 1) * 8;
    f32x4 acc[8];
#pragma unroll
    for (int n = 0; n < 8; ++n) acc[n] = (f32x4){0.f, 0.f, 0.f, 0.f};

    for (int p = 0; p < 4; ++p) {
        if (p) __syncthreads();      // previous panel fully consumed
        // stage B panel p: 64 gll of 1 KB (8 i-rows each); 8 per wave.
        // dest linear; source pre-swizzled: src chunk = (lds chunk)^(irow&7)
#pragma unroll
        for (int s = 0; s < 8; ++s) {
            const int g = s * 8 + wid;              // 0..63
            const int i0 = (g & 31) * 8;
            const u16* sg = (g >> 5) ? Ml : Mh;
            u16* dg = (g >> 5) ? Bl : Bh;
            const int irow = i0 + (lane >> 3);
            const int ch = (lane & 7) ^ (lane >> 3);
            async_copy16(sg + (size_t)irow * NREG + p * 64 + ch * 8,
                         dg + i0 * 64);
        }
        __syncthreads();             // drains vmcnt -> panel resident

#pragma unroll
        for (int kst = 0; kst < 2; ++kst) {
            const int achunk = (8 * p + 4 * kst + (lane >> 4)) ^ (lane & 7);
            short8 a_h = *(const short8*)(Ah + mrow * 256 + achunk * 8);
            short8 a_l = *(const short8*)(Al + mrow * 256 + achunk * 8);
#pragma unroll
            for (int n = 0; n < 8; ++n) {
                const int irow = (nh + n) * 16 + (lane & 15);
                const int bchunk = (4 * kst + (lane >> 4)) ^ (lane & 7);
                short8 b_h = *(const short8*)(Bh + irow * 64 + bchunk * 8);
                short8 b_l = *(const short8*)(Bl + irow * 64 + bchunk * 8);
                acc[n] = __builtin_amdgcn_mfma_f32_16x16x32_bf16(a_h, b_h, acc[n], 0, 0, 0);
                acc[n] = __builtin_amdgcn_mfma_f32_16x16x32_bf16(a_h, b_l, acc[n], 0, 0, 0);
                acc[n] = __builtin_amdgcn_mfma_f32_16x16x32_bf16(a_l, b_h, acc[n], 0, 0, 0);
            }
        }
    }

    // ---- epilogue: D col = lane&15 (i), row = (lane>>4)*4 + reg (t)
    const size_t tbase = t0 + (wid >> 1) * 16 + (lane >> 4) * 4;
#pragma unroll
    for (int n = 0; n < 8; ++n) {
#pragma unroll
        for (int r = 0; r < 4; ++r) {
            out[(tbase + r) * NREG + (nh + n) * 16 + (lane & 15)] = acc[n][r];
        }
    }
}

extern "C" void kernel_launch(void* const* d_in, const int* in_sizes, int n_in,
                              void* d_out, int out_size, void* d_ws, size_t ws_size,
                              hipStream_t stream) {
    const float* inputs  = (const float*)d_in[0];  // (16384, 256, 8)
    const float* kernels = (const float*)d_in[1];  // (256, 256, 16)
    const float* Wfeat   = (const float*)d_in[2];  // (1, 8)
    const float* Wlin    = (const float*)d_in[3];  // (1, 16)
    float* out = (float*)d_out;                    // (16384, 256)

    float* ws   = (float*)d_ws;                    // ~770 KB
    float* B    = ws;                              // 65536 f
    float* C    = B  + NREG * NREG;                // 65536 f (B^2)
    float* Einv = C  + NREG * NREG;                // 256 f
    u16*   Mh   = (u16*)(Einv + NREG);             // 65536 u16 (16B-aligned)
    u16*   Ml   = Mh + NREG * NREG;                // 65536 u16

    k_prep    <<<256, 256, 0, stream>>>(kernels, Wlin, Wfeat, B, Einv);
    k_mm      <<<256, 256, 0, stream>>>(B, B, C);
    k_mm2comb <<<256, 256, 0, stream>>>(B, C, Einv, Mh, Ml);
    k_main    <<<256, 512, 0, stream>>>(inputs, Wfeat, Mh, Ml, out);
}

// Round 16
// 50.304 us; speedup vs baseline: 1.7189x; 1.1200x over previous
//
#include <hip/hip_runtime.h>

// CRF-RNN collapsed: out[t,i] = sum_j M[i,j] * orig[t,j],
//   orig[t,j] = sum_m inputs[t,j,m]*W_feat[m]
//   M = (I + B + B^2 + B^3) * diag(1/denom) + B^4
// 3 dispatches:
//   k_prep -> B (fp32), Einv
//   k_rows -> per-row chain: B2_i = B_i*B, B3_i = B2_i*B, B4_i = B3_i*B
//             (full B is L2-resident; no materialized C) -> Mh/Ml row
//   k_main -> r15-verified: direct global->VGPR stream + B-panel MFMA

#define NREG 256   // N
#define KG   16    // gaussian kernels
#define MF   8     // features

typedef unsigned short u16;
typedef __attribute__((ext_vector_type(8))) short short8;   // 8 bf16 = 4 VGPR
typedef __attribute__((ext_vector_type(4))) float f32x4;

__device__ __forceinline__ void async_copy16(const void* g, void* l) {
    __builtin_amdgcn_global_load_lds(
        (const __attribute__((address_space(1))) void*)g,
        (__attribute__((address_space(3))) void*)l,
        16, 0, 0);
}

// inline-asm 16B global load: compiler must issue the batch where written.
__device__ __forceinline__ f32x4 ld16(const float* p) {
    f32x4 d;
    asm volatile("global_load_dwordx4 %0, %1, off" : "=v"(d) : "v"(p));
    return d;
}

__device__ __forceinline__ u16 bf16_rne(float x) {
    unsigned u = __float_as_uint(x);
    return (u16)((u + 0x7FFFu + ((u >> 16) & 1u)) >> 16);
}
__device__ __forceinline__ float bf16_to_f(u16 h) {
    return __uint_as_float(((unsigned)h) << 16);
}

// ---------------- K1: Kmat row, denom, B, Einv ----------------
__global__ __launch_bounds__(256) void k_prep(const float* __restrict__ kern,
                                              const float* __restrict__ Wlin,
                                              const float* __restrict__ Wfeat,
                                              float* __restrict__ B,
                                              float* __restrict__ Einv) {
    const int i = blockIdx.x, j = threadIdx.x;
    const float* kp = kern + ((size_t)i * NREG + j) * KG;
    float4 w0 = *(const float4*)(Wlin + 0);
    float4 w1 = *(const float4*)(Wlin + 4);
    float4 w2 = *(const float4*)(Wlin + 8);
    float4 w3 = *(const float4*)(Wlin + 12);
    float4 v0 = *(const float4*)(kp + 0);
    float4 v1 = *(const float4*)(kp + 4);
    float4 v2 = *(const float4*)(kp + 8);
    float4 v3 = *(const float4*)(kp + 12);
    float km = v0.x*w0.x + v0.y*w0.y + v0.z*w0.z + v0.w*w0.w
             + v1.x*w1.x + v1.y*w1.y + v1.z*w1.z + v1.w*w1.w
             + v2.x*w2.x + v2.y*w2.y + v2.z*w2.z + v2.w*w2.w
             + v3.x*w3.x + v3.y*w3.y + v3.z*w3.z + v3.w*w3.w;

    __shared__ float red[256];
    red[j] = km;
    __syncthreads();
    for (int s = 128; s > 0; s >>= 1) {
        if (j < s) red[j] += red[j + s];
        __syncthreads();
    }
    __shared__ float sden;
    if (j == 0) {
        float fw = 0.f;
#pragma unroll
        for (int m = 0; m < MF; ++m) fw += Wfeat[m];
        float den = fw + 2.f * red[0];
        sden = den;
        Einv[i] = 1.f / den;
    }
    __syncthreads();
    B[(size_t)i * NREG + j] = 2.f * km / sden;
}

// ---------------- K2: full power-chain per row -> Mh/Ml --------------------
// Grid 256 (block = row i), 512 thr: j = tid&255, h = tid>>8 splits the
// l-range in half (serial length 128/matmul). B (256 KB) is L2-resident.
__global__ __launch_bounds__(512) void k_rows(const float* __restrict__ B,
                                              const float* __restrict__ Einv,
                                              u16* __restrict__ Mh,
                                              u16* __restrict__ Ml) {
    const int i = blockIdx.x;
    const int j = threadIdx.x & 255;
    const int h = threadIdx.x >> 8;       // 0/1: l-half
    const int l0 = h * 128;
    __shared__ float rB[NREG], rP[NREG];  // B row / current power row
    __shared__ float part[2][NREG];

    if (h == 0) rB[j] = B[(size_t)i * NREG + j];
    __syncthreads();

#define ROWMM(rowv, dst_write)                                                \
    {                                                                         \
        float acc = 0.f;                                                      \
        _Pragma("unroll 4")                                                   \
        for (int l = l0; l < l0 + 128; l += 8) {                              \
            float b0 = B[(size_t)(l + 0) * NREG + j];                         \
            float b1 = B[(size_t)(l + 1) * NREG + j];                         \
            float b2 = B[(size_t)(l + 2) * NREG + j];                         \
            float b3 = B[(size_t)(l + 3) * NREG + j];                         \
            float b4 = B[(size_t)(l + 4) * NREG + j];                         \
            float b5 = B[(size_t)(l + 5) * NREG + j];                         \
            float b6 = B[(size_t)(l + 6) * NREG + j];                         \
            float b7 = B[(size_t)(l + 7) * NREG + j];                         \
            acc += rowv[l+0]*b0 + rowv[l+1]*b1 + rowv[l+2]*b2 + rowv[l+3]*b3  \
                 + rowv[l+4]*b4 + rowv[l+5]*b5 + rowv[l+6]*b6 + rowv[l+7]*b7; \
        }                                                                     \
        part[h][j] = acc;                                                     \
        __syncthreads();                                                      \
        dst_write                                                             \
        __syncthreads();                                                      \
    }

    float b2v = 0.f, b3v = 0.f, b4v = 0.f;
    // B^2 row
    ROWMM(rB,  { b2v = part[0][j] + part[1][j]; if (h == 0) rP[j] = b2v; })
    // B^3 row
    ROWMM(rP,  { b3v = part[0][j] + part[1][j]; if (h == 1) rP[j] = b3v; })
    // B^4 row  (rP now holds B^3; both halves read it before barrier inside)
    ROWMM(rP,  { b4v = part[0][j] + part[1][j]; })

    if (h == 0) {
        // b2v/b3v valid in h==0 threads (computed from part sums)
        const size_t idx = (size_t)i * NREG + j;
        float v = ((i == j) ? 1.f : 0.f) + rB[j] + b2v + b3v;
        v = v * Einv[j] + b4v;
        u16 hh = bf16_rne(v);
        Mh[idx] = hh;
        Ml[idx] = bf16_rne(v - bf16_to_f(hh));
    }
}

// ---------------- K3: fused feature-reduce + MFMA GEMM (r15-verified) ------
// Block = 512 thr (8 waves), 64 t-rows; grid 256 (1 block/CU).
// Stage 1: direct global->VGPR stream, inline-asm batched loads, 2-row
//          ping-pong, counted vmcnt(8). Stage 2: 4 K-panels of 64 j via
//          global_load_lds, split-bf16, 3 MFMA products.
__global__ __launch_bounds__(512, 1) void k_main(const float* __restrict__ in,
                                                 const float* __restrict__ Wfeat,
                                                 const u16* __restrict__ Mh,
                                                 const u16* __restrict__ Ml,
                                                 float* __restrict__ out) {
    __shared__ __align__(16) u16 Ah[64 * 256];       // 32 KB
    __shared__ __align__(16) u16 Al[64 * 256];       // 32 KB
    __shared__ __align__(16) u16 Bh[256 * 64];       // 32 KB
    __shared__ __align__(16) u16 Bl[256 * 64];       // 32 KB

    const int tid = threadIdx.x, lane = tid & 63, wid = tid >> 6;  // wid 0..7
    const size_t t0 = (size_t)blockIdx.x * 64;

    float4 wa = *(const float4*)(Wfeat);
    float4 wb = *(const float4*)(Wfeat + 4);
    asm volatile("" :: "v"(wa.x), "v"(wa.y), "v"(wa.z), "v"(wa.w),
                       "v"(wb.x), "v"(wb.y), "v"(wb.z), "v"(wb.w));

    // ---- stage 1 ----
    const float* rowbase = in + (t0 + wid * 8) * (NREG * MF);

#define ISSUE(BUF, TL)                                                        \
    {                                                                         \
        const float* rp_ = rowbase + (TL) * 2048 + lane * 8;                  \
        _Pragma("unroll")                                                     \
        for (int q = 0; q < 8; ++q)                                           \
            BUF[q] = ld16(rp_ + (q >> 1) * 512 + (q & 1) * 4);                \
    }

#define PROCESS(BUF, TL)                                                      \
    {                                                                         \
        const int t_ = wid * 8 + (TL);                                        \
        _Pragma("unroll")                                                     \
        for (int dq = 0; dq < 4; ++dq) {                                      \
            f32x4 a0 = BUF[2 * dq], a1 = BUF[2 * dq + 1];                     \
            float o = a0[0]*wa.x + a0[1]*wa.y + a0[2]*wa.z + a0[3]*wa.w       \
                    + a1[0]*wb.x + a1[1]*wb.y + a1[2]*wb.z + a1[3]*wb.w;      \
            u16 h_ = bf16_rne(o);                                             \
            u16 l_ = bf16_rne(o - bf16_to_f(h_));                             \
            const int j_ = dq * 64 + lane;                                    \
            const int idx_ = t_ * 256 + (((j_ >> 3) ^ (TL)) * 8) + (j_ & 7);  \
            Ah[idx_] = h_;                                                    \
            Al[idx_] = l_;                                                    \
        }                                                                     \
    }

#define WAITV(N)  asm volatile("s_waitcnt vmcnt(" #N ")" ::: "memory");       \
                  __builtin_amdgcn_sched_barrier(0);

    f32x4 ba[8], bb[8];
    ISSUE(ba, 0)
    ISSUE(bb, 1)
    WAITV(8)  PROCESS(ba, 0)  ISSUE(ba, 2)
    WAITV(8)  PROCESS(bb, 1)  ISSUE(bb, 3)
    WAITV(8)  PROCESS(ba, 2)  ISSUE(ba, 4)
    WAITV(8)  PROCESS(bb, 3)  ISSUE(bb, 5)
    WAITV(8)  PROCESS(ba, 4)  ISSUE(ba, 6)
    WAITV(8)  PROCESS(bb, 5)  ISSUE(bb, 7)
    WAITV(8)  PROCESS(ba, 6)
    WAITV(0)  PROCESS(bb, 7)

    __syncthreads();   // A splits resident

    // ---- stage 2: 4 K-panels of 64 j. Wave w: m-tile w>>1, n-half w&1.
    const int mrow = (wid >> 1) * 16 + (lane & 15);
    const int nh   = (wid & 1) * 8;
    f32x4 acc[8];
#pragma unroll
    for (int n = 0; n < 8; ++n) acc[n] = (f32x4){0.f, 0.f, 0.f, 0.f};

    for (int p = 0; p < 4; ++p) {
        if (p) __syncthreads();      // previous panel fully consumed
#pragma unroll
        for (int s = 0; s < 8; ++s) {
            const int g = s * 8 + wid;              // 0..63
            const int i0 = (g & 31) * 8;
            const u16* sg = (g >> 5) ? Ml : Mh;
            u16* dg = (g >> 5) ? Bl : Bh;
            const int irow = i0 + (lane >> 3);
            const int ch = (lane & 7) ^ (lane >> 3);
            async_copy16(sg + (size_t)irow * NREG + p * 64 + ch * 8,
                         dg + i0 * 64);
        }
        __syncthreads();             // drains vmcnt -> panel resident

#pragma unroll
        for (int kst = 0; kst < 2; ++kst) {
            const int achunk = (8 * p + 4 * kst + (lane >> 4)) ^ (lane & 7);
            short8 a_h = *(const short8*)(Ah + mrow * 256 + achunk * 8);
            short8 a_l = *(const short8*)(Al + mrow * 256 + achunk * 8);
#pragma unroll
            for (int n = 0; n < 8; ++n) {
                const int irow = (nh + n) * 16 + (lane & 15);
                const int bchunk = (4 * kst + (lane >> 4)) ^ (lane & 7);
                short8 b_h = *(const short8*)(Bh + irow * 64 + bchunk * 8);
                short8 b_l = *(const short8*)(Bl + irow * 64 + bchunk * 8);
                acc[n] = __builtin_amdgcn_mfma_f32_16x16x32_bf16(a_h, b_h, acc[n], 0, 0, 0);
                acc[n] = __builtin_amdgcn_mfma_f32_16x16x32_bf16(a_h, b_l, acc[n], 0, 0, 0);
                acc[n] = __builtin_amdgcn_mfma_f32_16x16x32_bf16(a_l, b_h, acc[n], 0, 0, 0);
            }
        }
    }

    // ---- epilogue: D col = lane&15 (i), row = (lane>>4)*4 + reg (t)
    const size_t tbase = t0 + (wid >> 1) * 16 + (lane >> 4) * 4;
#pragma unroll
    for (int n = 0; n < 8; ++n) {
#pragma unroll
        for (int r = 0; r < 4; ++r) {
            out[(tbase + r) * NREG + (nh + n) * 16 + (lane & 15)] = acc[n][r];
        }
    }
}

extern "C" void kernel_launch(void* const* d_in, const int* in_sizes, int n_in,
                              void* d_out, int out_size, void* d_ws, size_t ws_size,
                              hipStream_t stream) {
    const float* inputs  = (const float*)d_in[0];  // (16384, 256, 8)
    const float* kernels = (const float*)d_in[1];  // (256, 256, 16)
    const float* Wfeat   = (const float*)d_in[2];  // (1, 8)
    const float* Wlin    = (const float*)d_in[3];  // (1, 16)
    float* out = (float*)d_out;                    // (16384, 256)

    float* ws   = (float*)d_ws;                    // ~520 KB
    float* B    = ws;                              // 65536 f
    float* Einv = B + NREG * NREG;                 // 256 f
    u16*   Mh   = (u16*)(Einv + NREG);             // 65536 u16 (16B-aligned)
    u16*   Ml   = Mh + NREG * NREG;                // 65536 u16

    k_prep <<<256, 256, 0, stream>>>(kernels, Wlin, Wfeat, B, Einv);
    k_rows <<<256, 512, 0, stream>>>(B, Einv, Mh, Ml);
    k_main <<<256, 512, 0, stream>>>(inputs, Wfeat, Mh, Ml, out);
}